// Round 7
// baseline (4937.424 us; speedup 1.0000x reference)
//
#include <hip/hip_runtime.h>
#include <stdint.h>

#define D 512
#define BATCH 32
#define TT 2048
#define BT (BATCH*TT)   // 65536

typedef unsigned short u16;
typedef __attribute__((ext_vector_type(8))) short bf16x8;
typedef __attribute__((ext_vector_type(4))) float f32x4;
typedef __attribute__((ext_vector_type(4))) int i32x4;

__device__ __forceinline__ float bf2f(u16 u){
  union { unsigned int i; float f; } v; v.i = ((unsigned int)u) << 16; return v.f;
}
__device__ __forceinline__ u16 f2bf(float f){
  union { float f; unsigned int i; } v; v.f = f;
  unsigned int r = (v.i + 0x7fffu + ((v.i >> 16) & 1u)) >> 16;
  return (u16)r;
}

__device__ __forceinline__ int dot4i8(int a, int b, int c){
#if __has_builtin(__builtin_amdgcn_sdot4)
  return __builtin_amdgcn_sdot4(a, b, c, false);
#else
  c += (int)(char)(a      ) * (int)(char)(b      );
  c += (int)(char)(a >>  8) * (int)(char)(b >>  8);
  c += (int)(char)(a >> 16) * (int)(char)(b >> 16);
  c += (int)(char)(a >> 24) * (int)(char)(b >> 24);
  return c;
#endif
}

__device__ __forceinline__ float fast_rcp(float x){
#if __has_builtin(__builtin_amdgcn_rcpf)
  return __builtin_amdgcn_rcpf(x);
#else
  return 1.f / x;
#endif
}

// ---------------- rmsnorm: xn = x/max(||x||,1e-12) * sqrt(D) * (gamma+1) ---
__global__ __launch_bounds__(256) void rmsnorm_k(const float* __restrict__ x,
                                                 const float* __restrict__ gamma,
                                                 u16* __restrict__ xn){
  int row = blockIdx.x;
  int t = threadIdx.x;
  const float* xr = x + (size_t)row * D;
  float v0 = xr[t];
  float v1 = xr[t + 256];
  float s = v0*v0 + v1*v1;
  #pragma unroll
  for (int o = 32; o > 0; o >>= 1) s += __shfl_down(s, o);
  __shared__ float red[4];
  int lane = t & 63, wv = t >> 6;
  if (lane == 0) red[wv] = s;
  __syncthreads();
  float tot = red[0] + red[1] + red[2] + red[3];
  float n = fmaxf(sqrtf(tot), 1e-12f);
  float sc = 22.627416997969522f / n;   // sqrt(512)
  u16* o_ = xn + (size_t)row * D;
  o_[t]       = f2bf(v0 * sc * (gamma[t] + 1.f));
  o_[t + 256] = f2bf(v1 * sc * (gamma[t + 256] + 1.f));
}

// -------- 512x512 transpose + fp32->bf16 convert (dst[n][k] = src[k][n]) ---
__global__ __launch_bounds__(256) void transpose_k(const float* __restrict__ src,
                                                   u16* __restrict__ dst){
  __shared__ u16 tile[32][33];
  int bx = blockIdx.x * 32, by = blockIdx.y * 32;
  int tx = threadIdx.x & 31, ty = threadIdx.x >> 5;   // 32 x 8
  #pragma unroll
  for (int i = 0; i < 32; i += 8)
    tile[ty + i][tx] = f2bf(src[(size_t)(by + ty + i) * D + bx + tx]);
  __syncthreads();
  #pragma unroll
  for (int i = 0; i < 32; i += 8)
    dst[(size_t)(bx + ty + i) * D + by + tx] = tile[tx][ty + i];
}

// -------- per-column int8 quantization of Whf (fp32 in) -------------------
// Wq[e*128 + w] packs k = 4w..4w+3 of column e (byte 0 = lowest k).
__global__ __launch_bounds__(64) void quant_col_k(const float* __restrict__ W,
                                                  int* __restrict__ Wq,
                                                  float* __restrict__ sc){
  int e = blockIdx.x;        // column index
  int lane = threadIdx.x;    // 64 lanes, each covers 8 d's
  float w[8];
  float m = 0.f;
  #pragma unroll
  for (int j = 0; j < 8; j++){
    w[j] = W[(size_t)(lane*8 + j) * D + e];
    m = fmaxf(m, fabsf(w[j]));
  }
  #pragma unroll
  for (int o = 32; o > 0; o >>= 1) m = fmaxf(m, __shfl_xor(m, o));
  float inv = (m > 0.f) ? (127.f / m) : 0.f;
  int q[8];
  #pragma unroll
  for (int j = 0; j < 8; j++){
    int v = __float2int_rn(w[j] * inv);
    v = v < -127 ? -127 : (v > 127 ? 127 : v);
    q[j] = v & 0xff;
  }
  int p0 = q[0] | (q[1] << 8) | (q[2] << 16) | (q[3] << 24);
  int p1 = q[4] | (q[5] << 8) | (q[6] << 16) | (q[7] << 24);
  Wq[e*128 + lane*2]     = p0;
  Wq[e*128 + lane*2 + 1] = p1;
  if (lane == 0) sc[e] = m / (127.f * 127.f);
}

// ---------------- bf16 GEMM: C[m][n] = sum_k A[m][k]*Bt[n][k] -------------
// (round-3 proven, unchanged)
__global__ __launch_bounds__(256) void gemm_bt_k(const u16* __restrict__ A,
                                                 const u16* __restrict__ Bt,
                                                 u16* __restrict__ C,
                                                 int do_tanh){
  __shared__ __align__(16) u16 As[128*32];
  __shared__ __align__(16) u16 Bs[128*32];
  int tid = threadIdx.x;
  int bm = blockIdx.x, bn = blockIdx.y;
  int wv = tid >> 6, lane = tid & 63;
  int wm = (wv & 1) * 64, wn = (wv >> 1) * 64;
  int m0 = lane & 15, quad = lane >> 4;
  f32x4 acc[4][4];
  #pragma unroll
  for (int i = 0; i < 4; i++)
    #pragma unroll
    for (int j = 0; j < 4; j++){
      f32x4 z = {0.f, 0.f, 0.f, 0.f};
      acc[i][j] = z;
    }
  const size_t arow = (size_t)bm * 128;
  const size_t brow = (size_t)bn * 128;
  for (int k0 = 0; k0 < D; k0 += 32){
    __syncthreads();
    #pragma unroll
    for (int i = 0; i < 2; i++){
      int c = tid + 256*i;
      int r = c >> 2, ko = (c & 3) * 8;
      ((int4*)As)[c] = *(const int4*)(A  + (arow + r) * D + k0 + ko);
      ((int4*)Bs)[c] = *(const int4*)(Bt + (brow + r) * D + k0 + ko);
    }
    __syncthreads();
    bf16x8 af[4], bfr[4];
    #pragma unroll
    for (int i = 0; i < 4; i++){
      af[i]  = *(const bf16x8*)(As + (wm + i*16 + m0) * 32 + quad*8);
      bfr[i] = *(const bf16x8*)(Bs + (wn + i*16 + m0) * 32 + quad*8);
    }
    #pragma unroll
    for (int i = 0; i < 4; i++)
      #pragma unroll
      for (int j = 0; j < 4; j++)
        acc[i][j] = __builtin_amdgcn_mfma_f32_16x16x32_bf16(af[i], bfr[j], acc[i][j], 0, 0, 0);
  }
  #pragma unroll
  for (int i = 0; i < 4; i++)
    #pragma unroll
    for (int j = 0; j < 4; j++)
      #pragma unroll
      for (int r = 0; r < 4; r++){
        size_t row = arow + wm + i*16 + quad*4 + r;
        int col = bn*128 + wn + j*16 + m0;
        float v = acc[i][j][r];
        if (do_tanh) v = tanhf(v);
        C[row * D + col] = f2bf(v);
      }
}

// ---------------- sequential LRU scan: dual-pipe (VALU + MFMA) ------------
// 1 batch per block, 32 blocks, 512 threads (proven config). Per step the
// matvec is split across BOTH pipes (they overlap, m114):
//   dims 0..255  -> VALU sdot4. Lane pair (l, l^32) of wave wv shares dim
//     wv*32+(l&31): each lane covers its K-half (64 words, 16 ds_read_b128
//     broadcast reads), 4 independent sdot chains of 16, then ONE
//     __shfl_xor(32) + add completes z (exact int).
//   dims 256..511 -> MFMA mfma_i32_16x16x64_i8, h replicated in M (idle
//     matrix pipe, so the 16x replication is free). Wave wv owns tiles
//     j=0,1 -> cols 256+wv*32+j*16+lo. B-frags register-stationary
//     (bf[2][8] from Wq, R6-HW-verified layout); A-frags = 8 broadcast
//     ds_read_b128 per wave. z = acc[j][0] (any replica row).
// Every lane owns exactly ONE output dim:
//   e_own = (l<32) ? wv*32+l : 256+wv*32+(l-32)
// -> fully uniform epilogue (z select + sigmoid + store + quant + ds_write).
// z exact-integer on both paths -> numerics identical to prior rounds.
__global__ __launch_bounds__(512, 1) void lru_scan_k(u16* __restrict__ Nn,        // tanh(x@Wn), becomes H
                                                     const u16* __restrict__ Ff,  // x@Wif
                                                     const int* __restrict__ Wq,
                                                     const float* __restrict__ sc,
                                                     const float* __restrict__ bhf){
  int tid = threadIdx.x;
  int b = blockIdx.x;
  int wv = tid >> 6, l = tid & 63;
  int half = l >> 5;          // 0 = low-K / sdot owner, 1 = high-K / mfma owner
  int l31 = l & 31;
  int lo = l & 15, hi = l >> 4;

  int ds_dim = wv*32 + l31;                 // sdot dim this lane contributes to
  int e_own  = half ? (256 + wv*32 + l31)   // dim this lane finalizes
                    : ds_dim;

  // sdot weights: my K-half (words half*64 .. half*64+63) of column ds_dim
  int4 wsd[16];
  {
    const int* wp = Wq + (size_t)ds_dim * 128 + half*64;
    #pragma unroll
    for (int i = 0; i < 16; i++) wsd[i] = ((const int4*)wp)[i];
  }
  // MFMA B-frags: bf[j][c] supplies B[k=c*64+hi*16+i][n=256+wv*32+j*16+lo]
  i32x4 bf[2][8];
  #pragma unroll
  for (int j = 0; j < 2; j++){
    const int* wpm = Wq + (size_t)(256 + wv*32 + j*16 + lo) * 128;
    #pragma unroll
    for (int c = 0; c < 8; c++)
      bf[j][c] = *(const i32x4*)(wpm + c*16 + hi*4);
  }
  float scale = sc[e_own];
  float bias  = bhf[e_own];

  __shared__ __align__(16) char hq[2][512];
  if (tid < 128) ((int*)hq[0])[tid] = 0;
  float h = 0.f;
  const size_t gb = (size_t)b * TT * D;
  u16* npc = Nn + gb + e_own;
  const u16* fpc = Ff + gb + e_own;
  u16 nv = npc[0], fv = fpc[0];
  __syncthreads();

  for (int t = 0; t < TT; t++){
    const char* hb = hq[t & 1];
    // ---- VALU path: 4 independent sdot chains over my 256-B K-half
    int p0 = 0, p1 = 0, p2 = 0, p3 = 0;
    const int4* ha = (const int4*)(hb + half*256);
    #pragma unroll
    for (int i = 0; i < 16; i++){
      int4 a = ha[i];
      p0 = dot4i8(wsd[i].x, a.x, p0);
      p1 = dot4i8(wsd[i].y, a.y, p1);
      p2 = dot4i8(wsd[i].z, a.z, p2);
      p3 = dot4i8(wsd[i].w, a.w, p3);
    }
    int zd = (p0 + p1) + (p2 + p3);
    zd += __shfl_xor(zd, 32);               // full-K sum for ds_dim
    // ---- MFMA path: 2 tiles, 8 chained K-steps each (matrix pipe)
    i32x4 acc0 = {0,0,0,0}, acc1 = {0,0,0,0};
    #pragma unroll
    for (int c = 0; c < 8; c++){
      i32x4 a = *(const i32x4*)(hb + c*64 + hi*16);   // broadcast-16
      acc0 = __builtin_amdgcn_mfma_i32_16x16x64_i8(a, bf[0][c], acc0, 0, 0, 0);
      acc1 = __builtin_amdgcn_mfma_i32_16x16x64_i8(a, bf[1][c], acc1, 0, 0, 0);
    }
    // z select: sdot owners (l<32) take zd; mfma owners take acc[hi-2][0]
    int zm = (hi == 2) ? acc0[0] : acc1[0];
    int z  = half ? zm : zd;
    // ---- uniform epilogue (every lane, its own dim)
    float arg = (float)z * scale + bf2f(fv) + bias;
    float g = fast_rcp(1.f + __expf(-arg));
    h = h + g * (bf2f(nv) - h);
    *npc = f2bf(h);                          // overwrite Nn with H (row t)
    int q = __float2int_rn(h * 127.f);
    q = q < -127 ? -127 : (q > 127 ? 127 : q);
    hq[(t + 1) & 1][e_own] = (char)q;
    size_t dn = (t + 1 < TT) ? (size_t)D : (size_t)0;   // uniform select
    nv = npc[dn];                            // prefetch row t+1 (or dead reread)
    fv = fpc[dn];
    npc += D; fpc += D;
    // drain LDS ops, then barrier (global ops may stay in flight)
    asm volatile("s_waitcnt lgkmcnt(0)\n\ts_barrier" ::: "memory");
  }
}

// ---------------- final gate_cell, pass 1: lru -> (in-place over Nng) -----
__global__ __launch_bounds__(256) void final1_k(const u16* __restrict__ xn,
                                                u16* __restrict__ Nng,        // tanh(h1@gWn), becomes lru
                                                const u16* __restrict__ Ffg,  // h1@gWif
                                                const u16* __restrict__ Ghf,  // xn@gWhf
                                                const float* __restrict__ gbhf){
  size_t i = (size_t)blockIdx.x * 256 + threadIdx.x;
  int e = (int)(i & (D - 1));
  float xnv = bf2f(xn[i]);
  float nv  = bf2f(Nng[i]);
  float arg = bf2f(Ghf[i]) + gbhf[e] + bf2f(Ffg[i]);
  float g = 1.f / (1.f + __expf(-arg));
  float lru = xnv + g * (nv - xnv);
  Nng[i] = f2bf(lru);
}

// ---------------- final pass 2: out = lru + x (fp32) ----------------------
__global__ __launch_bounds__(256) void final2_k(const u16* __restrict__ lru,
                                                const float* __restrict__ x,
                                                float* __restrict__ out){
  size_t i = (size_t)blockIdx.x * 256 + threadIdx.x;
  out[i] = bf2f(lru[i]) + x[i];
}

extern "C" void kernel_launch(void* const* d_in, const int* in_sizes, int n_in,
                              void* d_out, int out_size, void* d_ws, size_t ws_size,
                              hipStream_t stream){
  const float* x      = (const float*)d_in[0];
  const float* gamma  = (const float*)d_in[1];
  const float* g_Wn   = (const float*)d_in[2];
  const float* g_Wif  = (const float*)d_in[3];
  const float* g_Whf  = (const float*)d_in[4];
  const float* g_bhf  = (const float*)d_in[5];
  const float* l0_Wn  = (const float*)d_in[6];
  const float* l0_Wif = (const float*)d_in[7];
  const float* l0_Whf = (const float*)d_in[8];
  const float* l0_bhf = (const float*)d_in[9];
  const float* l1_Wn  = (const float*)d_in[10];
  const float* l1_Wif = (const float*)d_in[11];
  const float* l1_Whf = (const float*)d_in[12];
  const float* l1_bhf = (const float*)d_in[13];
  float* out = (float*)d_out;

  // ---- plane layout: P0,P1 in ws; P2,P3 inside d_out (2 bf16 planes = 134MB)
  char* ws = (char*)d_ws;
  const size_t PLANE = (size_t)BT * D * 2;      // 67.1 MB bf16 plane
  u16* P0 = (u16*)(ws);                         // xn (live to the end)
  u16* P1 = (u16*)(ws + PLANE);                 // Nn0/H0, then Nn_g, then lru
  u16* P2 = (u16*)d_out;                        // Ff planes
  u16* P3 = P2 + (size_t)BT * D;                // Nn1/H1, then Ghf

  char* wb = ws + 2*PLANE;
  const size_t WSZ = (size_t)D * D * 2;         // 512 KB per transposed bf16 weight
  u16* T_l0Wn  = (u16*)(wb + 0*WSZ);
  u16* T_l0Wif = (u16*)(wb + 1*WSZ);
  u16* T_gWhf  = (u16*)(wb + 2*WSZ);
  u16* T_l1Wn  = (u16*)(wb + 3*WSZ);
  u16* T_l1Wif = (u16*)(wb + 4*WSZ);
  u16* T_gWn   = (u16*)(wb + 5*WSZ);
  u16* T_gWif  = (u16*)(wb + 6*WSZ);
  int*   Wq0 = (int*)  (wb + 7*WSZ);
  int*   Wq1 = (int*)  (wb + 7*WSZ + (size_t)D*D);
  float* sc0 = (float*)(wb + 7*WSZ + 2*(size_t)D*D);
  float* sc1 = (float*)(wb + 7*WSZ + 2*(size_t)D*D + D*4);

  dim3 tb(256), tg(16, 16);
  // weight prep (tiny)
  transpose_k<<<tg, tb, 0, stream>>>(l0_Wn,  T_l0Wn);
  transpose_k<<<tg, tb, 0, stream>>>(l0_Wif, T_l0Wif);
  transpose_k<<<tg, tb, 0, stream>>>(g_Whf,  T_gWhf);
  transpose_k<<<tg, tb, 0, stream>>>(l1_Wn,  T_l1Wn);
  transpose_k<<<tg, tb, 0, stream>>>(l1_Wif, T_l1Wif);
  transpose_k<<<tg, tb, 0, stream>>>(g_Wn,   T_gWn);
  transpose_k<<<tg, tb, 0, stream>>>(g_Wif,  T_gWif);
  quant_col_k<<<512, 64, 0, stream>>>(l0_Whf, Wq0, sc0);
  quant_col_k<<<512, 64, 0, stream>>>(l1_Whf, Wq1, sc1);

  rmsnorm_k<<<BT, 256, 0, stream>>>(x, gamma, P0);

  dim3 gg(BT/128, D/128);
  // layer 0
  gemm_bt_k<<<gg, tb, 0, stream>>>(P0, T_l0Wn,  P1, 1);   // Nn0
  gemm_bt_k<<<gg, tb, 0, stream>>>(P0, T_l0Wif, P2, 0);   // Ff0
  lru_scan_k<<<BATCH, 512, 0, stream>>>(P1, P2, Wq0, sc0, l0_bhf);  // H0 -> P1
  // layer 1
  gemm_bt_k<<<gg, tb, 0, stream>>>(P1, T_l1Wn,  P3, 1);   // Nn1
  gemm_bt_k<<<gg, tb, 0, stream>>>(P1, T_l1Wif, P2, 0);   // Ff1
  lru_scan_k<<<BATCH, 512, 0, stream>>>(P3, P2, Wq1, sc1, l1_bhf);  // H1 -> P3
  // gate cell projections (H0 dead -> P1, Ff1 dead -> P2)
  gemm_bt_k<<<gg, tb, 0, stream>>>(P3, T_gWn,  P1, 1);    // Nn_g
  gemm_bt_k<<<gg, tb, 0, stream>>>(P3, T_gWif, P2, 0);    // Ff_g
  gemm_bt_k<<<gg, tb, 0, stream>>>(P0, T_gWhf, P3, 0);    // Ghf (H1 dead)

  final1_k<<<BT*D/256, 256, 0, stream>>>(P0, P1, P2, P3, g_bhf);  // lru -> P1
  final2_k<<<BT*D/256, 256, 0, stream>>>(P1, x, out);
}

// Round 8
// 4395.905 us; speedup vs baseline: 1.1232x; 1.1232x over previous
//
#include <hip/hip_runtime.h>
#include <stdint.h>

#define D 512
#define BATCH 32
#define TT 2048
#define BT (BATCH*TT)   // 65536

typedef unsigned short u16;
typedef __attribute__((ext_vector_type(8))) short bf16x8;
typedef __attribute__((ext_vector_type(4))) float f32x4;

__device__ __forceinline__ float bf2f(u16 u){
  union { unsigned int i; float f; } v; v.i = ((unsigned int)u) << 16; return v.f;
}
__device__ __forceinline__ u16 f2bf(float f){
  union { float f; unsigned int i; } v; v.f = f;
  unsigned int r = (v.i + 0x7fffu + ((v.i >> 16) & 1u)) >> 16;
  return (u16)r;
}

__device__ __forceinline__ int dot4i8(int a, int b, int c){
#if __has_builtin(__builtin_amdgcn_sdot4)
  return __builtin_amdgcn_sdot4(a, b, c, false);
#else
  c += (int)(char)(a      ) * (int)(char)(b      );
  c += (int)(char)(a >>  8) * (int)(char)(b >>  8);
  c += (int)(char)(a >> 16) * (int)(char)(b >> 16);
  c += (int)(char)(a >> 24) * (int)(char)(b >> 24);
  return c;
#endif
}

// ---------------- rmsnorm: xn = x/max(||x||,1e-12) * sqrt(D) * (gamma+1) ---
__global__ __launch_bounds__(256) void rmsnorm_k(const float* __restrict__ x,
                                                 const float* __restrict__ gamma,
                                                 u16* __restrict__ xn){
  int row = blockIdx.x;
  int t = threadIdx.x;
  const float* xr = x + (size_t)row * D;
  float v0 = xr[t];
  float v1 = xr[t + 256];
  float s = v0*v0 + v1*v1;
  #pragma unroll
  for (int o = 32; o > 0; o >>= 1) s += __shfl_down(s, o);
  __shared__ float red[4];
  int lane = t & 63, wv = t >> 6;
  if (lane == 0) red[wv] = s;
  __syncthreads();
  float tot = red[0] + red[1] + red[2] + red[3];
  float n = fmaxf(sqrtf(tot), 1e-12f);
  float sc = 22.627416997969522f / n;   // sqrt(512)
  u16* o_ = xn + (size_t)row * D;
  o_[t]       = f2bf(v0 * sc * (gamma[t] + 1.f));
  o_[t + 256] = f2bf(v1 * sc * (gamma[t + 256] + 1.f));
}

// -------- 7x batched 512x512 transpose + fp32->bf16 (dst[n][k]=src[k][n]) --
__global__ __launch_bounds__(256) void transpose7_k(
    const float* __restrict__ s0, const float* __restrict__ s1,
    const float* __restrict__ s2, const float* __restrict__ s3,
    const float* __restrict__ s4, const float* __restrict__ s5,
    const float* __restrict__ s6,
    u16* __restrict__ d0, u16* __restrict__ d1, u16* __restrict__ d2,
    u16* __restrict__ d3, u16* __restrict__ d4, u16* __restrict__ d5,
    u16* __restrict__ d6){
  const float* src; u16* dst;
  switch (blockIdx.z){
    case 0: src = s0; dst = d0; break;
    case 1: src = s1; dst = d1; break;
    case 2: src = s2; dst = d2; break;
    case 3: src = s3; dst = d3; break;
    case 4: src = s4; dst = d4; break;
    case 5: src = s5; dst = d5; break;
    default: src = s6; dst = d6; break;
  }
  __shared__ u16 tile[32][33];
  int bx = blockIdx.x * 32, by = blockIdx.y * 32;
  int tx = threadIdx.x & 31, ty = threadIdx.x >> 5;   // 32 x 8
  #pragma unroll
  for (int i = 0; i < 32; i += 8)
    tile[ty + i][tx] = f2bf(src[(size_t)(by + ty + i) * D + bx + tx]);
  __syncthreads();
  #pragma unroll
  for (int i = 0; i < 32; i += 8)
    dst[(size_t)(bx + ty + i) * D + by + tx] = tile[tx][ty + i];
}

// -------- per-column int8 quantization of BOTH Whf matrices ----------------
// Wq[e*128 + w] packs k = 4w..4w+3 of column e (byte 0 = lowest k).
__global__ __launch_bounds__(64) void quant2_k(const float* __restrict__ W0,
                                               const float* __restrict__ W1,
                                               int* __restrict__ Wq0,
                                               int* __restrict__ Wq1,
                                               float* __restrict__ sc0,
                                               float* __restrict__ sc1){
  int bid = blockIdx.x;
  int e = bid & (D - 1);
  const float* W = (bid < D) ? W0 : W1;
  int*   Wq      = (bid < D) ? Wq0 : Wq1;
  float* sc      = (bid < D) ? sc0 : sc1;
  int lane = threadIdx.x;    // 64 lanes, each covers 8 d's
  float w[8];
  float m = 0.f;
  #pragma unroll
  for (int j = 0; j < 8; j++){
    w[j] = W[(size_t)(lane*8 + j) * D + e];
    m = fmaxf(m, fabsf(w[j]));
  }
  #pragma unroll
  for (int o = 32; o > 0; o >>= 1) m = fmaxf(m, __shfl_xor(m, o));
  float inv = (m > 0.f) ? (127.f / m) : 0.f;
  int q[8];
  #pragma unroll
  for (int j = 0; j < 8; j++){
    int v = __float2int_rn(w[j] * inv);
    v = v < -127 ? -127 : (v > 127 ? 127 : v);
    q[j] = v & 0xff;
  }
  int p0 = q[0] | (q[1] << 8) | (q[2] << 16) | (q[3] << 24);
  int p1 = q[4] | (q[5] << 8) | (q[6] << 16) | (q[7] << 24);
  Wq[e*128 + lane*2]     = p0;
  Wq[e*128 + lane*2 + 1] = p1;
  if (lane == 0) sc[e] = m / (127.f * 127.f);
}

// ---------------- bf16 GEMM: C[m][n] = sum_k A[m][k]*Bt[n][k] -------------
// (round-3 proven, unchanged — used for the single Ghf projection)
__global__ __launch_bounds__(256) void gemm_bt_k(const u16* __restrict__ A,
                                                 const u16* __restrict__ Bt,
                                                 u16* __restrict__ C,
                                                 int do_tanh){
  __shared__ __align__(16) u16 As[128*32];
  __shared__ __align__(16) u16 Bs[128*32];
  int tid = threadIdx.x;
  int bm = blockIdx.x, bn = blockIdx.y;
  int wv = tid >> 6, lane = tid & 63;
  int wm = (wv & 1) * 64, wn = (wv >> 1) * 64;
  int m0 = lane & 15, quad = lane >> 4;
  f32x4 acc[4][4];
  #pragma unroll
  for (int i = 0; i < 4; i++)
    #pragma unroll
    for (int j = 0; j < 4; j++){
      f32x4 z = {0.f, 0.f, 0.f, 0.f};
      acc[i][j] = z;
    }
  const size_t arow = (size_t)bm * 128;
  const size_t brow = (size_t)bn * 128;
  for (int k0 = 0; k0 < D; k0 += 32){
    __syncthreads();
    #pragma unroll
    for (int i = 0; i < 2; i++){
      int c = tid + 256*i;
      int r = c >> 2, ko = (c & 3) * 8;
      ((int4*)As)[c] = *(const int4*)(A  + (arow + r) * D + k0 + ko);
      ((int4*)Bs)[c] = *(const int4*)(Bt + (brow + r) * D + k0 + ko);
    }
    __syncthreads();
    bf16x8 af[4], bfr[4];
    #pragma unroll
    for (int i = 0; i < 4; i++){
      af[i]  = *(const bf16x8*)(As + (wm + i*16 + m0) * 32 + quad*8);
      bfr[i] = *(const bf16x8*)(Bs + (wn + i*16 + m0) * 32 + quad*8);
    }
    #pragma unroll
    for (int i = 0; i < 4; i++)
      #pragma unroll
      for (int j = 0; j < 4; j++)
        acc[i][j] = __builtin_amdgcn_mfma_f32_16x16x32_bf16(af[i], bfr[j], acc[i][j], 0, 0, 0);
  }
  #pragma unroll
  for (int i = 0; i < 4; i++)
    #pragma unroll
    for (int j = 0; j < 4; j++)
      #pragma unroll
      for (int r = 0; r < 4; r++){
        size_t row = arow + wm + i*16 + quad*4 + r;
        int col = bn*128 + wn + j*16 + m0;
        float v = acc[i][j][r];
        if (do_tanh) v = tanhf(v);
        C[row * D + col] = f2bf(v);
      }
}

// ------- dual-B bf16 GEMM: C1 = tanh?(A@B1t^T), C2 = A@B2t^T --------------
// A staged ONCE into LDS and reused for both products (the Wn/Wif pairs
// always share A). Staging traffic per output halves; dispatches halve.
__global__ __launch_bounds__(256) void gemm_bt2_k(const u16* __restrict__ A,
                                                  const u16* __restrict__ B1t,
                                                  const u16* __restrict__ B2t,
                                                  u16* __restrict__ C1,
                                                  u16* __restrict__ C2){
  __shared__ __align__(16) u16 As[128*32];
  __shared__ __align__(16) u16 B1s[128*32];
  __shared__ __align__(16) u16 B2s[128*32];
  int tid = threadIdx.x;
  int bm = blockIdx.x, bn = blockIdx.y;
  int wv = tid >> 6, lane = tid & 63;
  int wm = (wv & 1) * 64, wn = (wv >> 1) * 64;
  int m0 = lane & 15, quad = lane >> 4;
  f32x4 acc1[4][4], acc2[4][4];
  #pragma unroll
  for (int i = 0; i < 4; i++)
    #pragma unroll
    for (int j = 0; j < 4; j++){
      f32x4 z = {0.f, 0.f, 0.f, 0.f};
      acc1[i][j] = z; acc2[i][j] = z;
    }
  const size_t arow = (size_t)bm * 128;
  const size_t brow = (size_t)bn * 128;
  for (int k0 = 0; k0 < D; k0 += 32){
    __syncthreads();
    #pragma unroll
    for (int i = 0; i < 2; i++){
      int c = tid + 256*i;
      int r = c >> 2, ko = (c & 3) * 8;
      ((int4*)As)[c]  = *(const int4*)(A   + (arow + r) * D + k0 + ko);
      ((int4*)B1s)[c] = *(const int4*)(B1t + (brow + r) * D + k0 + ko);
      ((int4*)B2s)[c] = *(const int4*)(B2t + (brow + r) * D + k0 + ko);
    }
    __syncthreads();
    bf16x8 af[4], b1f[4], b2f[4];
    #pragma unroll
    for (int i = 0; i < 4; i++){
      af[i]  = *(const bf16x8*)(As  + (wm + i*16 + m0) * 32 + quad*8);
      b1f[i] = *(const bf16x8*)(B1s + (wn + i*16 + m0) * 32 + quad*8);
      b2f[i] = *(const bf16x8*)(B2s + (wn + i*16 + m0) * 32 + quad*8);
    }
    #pragma unroll
    for (int i = 0; i < 4; i++)
      #pragma unroll
      for (int j = 0; j < 4; j++){
        acc1[i][j] = __builtin_amdgcn_mfma_f32_16x16x32_bf16(af[i], b1f[j], acc1[i][j], 0, 0, 0);
        acc2[i][j] = __builtin_amdgcn_mfma_f32_16x16x32_bf16(af[i], b2f[j], acc2[i][j], 0, 0, 0);
      }
  }
  #pragma unroll
  for (int i = 0; i < 4; i++)
    #pragma unroll
    for (int j = 0; j < 4; j++)
      #pragma unroll
      for (int r = 0; r < 4; r++){
        size_t row = arow + wm + i*16 + quad*4 + r;
        int col = bn*128 + wn + j*16 + m0;
        C1[row * D + col] = f2bf(tanhf(acc1[i][j][r]));
        C2[row * D + col] = f2bf(acc2[i][j][r]);
      }
}

// ---------------- sequential LRU scan (round-3 proven, verbatim) ----------
// K-split-4 VALU matvec. Lanes {m, m+16, m+32, m+48} of a wave form a quad;
// quad (wv, m) owns output dims base = wv*64 + m*4 + {0..3}. Each lane:
//   - holds weights for all 4 dims over ITS K-quarter (words q2*32..+31)
//   - reads only 128 B of h per step (8 ds_read_b128)
//   - 2-stage integer __shfl_xor(16/32) reduce-transpose lands the exact
//     sum for dim base+q2 on this lane (int adds associative -> bit-identical)
// Writes H IN-PLACE over Nn (each lane touches only its own column e).
__global__ __launch_bounds__(512, 2) void lru_scan_k(u16* __restrict__ Nn,        // tanh(x@Wn), becomes H
                                                     const u16* __restrict__ Ff,  // x@Wif
                                                     const int* __restrict__ Wq,
                                                     const float* __restrict__ sc,
                                                     const float* __restrict__ bhf){
  int tid = threadIdx.x;
  int b = blockIdx.x;
  int wv = tid >> 6, l = tid & 63;
  int m  = l & 15;          // quad id within wave
  int q2 = l >> 4;          // position within quad = K-chunk = final dim offset
  int base_e = wv*64 + m*4;
  int e = base_e + q2;      // dim this lane finalizes

  // weights: 4 dims x my K-quarter (words q2*32 .. q2*32+31)
  int4 wq[4][8];
  #pragma unroll
  for (int j = 0; j < 4; j++){
    const int* wp = Wq + (size_t)(base_e + j) * 128 + q2*32;
    #pragma unroll
    for (int i = 0; i < 8; i++) wq[j][i] = ((const int4*)wp)[i];
  }
  float scale = sc[e];
  float bias  = bhf[e];

  __shared__ __align__(16) char hq[2][512];
  if (tid < 128) ((int*)hq[0])[tid] = 0;
  float h = 0.f;
  const size_t base = (size_t)b * TT * D + e;
  u16* np = Nn + base;
  const u16* fp = Ff + base;
  float nv  = bf2f(np[0]);
  float fvb = bf2f(fp[0]) + bias;
  __syncthreads();

  for (int t = 0; t < TT; t++){
    float nv_n = 0.f, fvb_n = 0.f;
    if (t < TT - 1){
      nv_n  = bf2f(np[(size_t)(t+1) * D]);
      fvb_n = bf2f(fp[(size_t)(t+1) * D]) + bias;
    }
    const char* hb = hq[t & 1] + q2*128;   // my 128-B quarter of h
    int p0 = 0, p1 = 0, p2 = 0, p3 = 0;    // partials for dims base_e+0..3
    #pragma unroll
    for (int i = 0; i < 8; i++){
      int4 a = ((const int4*)hb)[i];
      p0 = dot4i8(wq[0][i].x, a.x, p0); p0 = dot4i8(wq[0][i].y, a.y, p0);
      p0 = dot4i8(wq[0][i].z, a.z, p0); p0 = dot4i8(wq[0][i].w, a.w, p0);
      p1 = dot4i8(wq[1][i].x, a.x, p1); p1 = dot4i8(wq[1][i].y, a.y, p1);
      p1 = dot4i8(wq[1][i].z, a.z, p1); p1 = dot4i8(wq[1][i].w, a.w, p1);
      p2 = dot4i8(wq[2][i].x, a.x, p2); p2 = dot4i8(wq[2][i].y, a.y, p2);
      p2 = dot4i8(wq[2][i].z, a.z, p2); p2 = dot4i8(wq[2][i].w, a.w, p2);
      p3 = dot4i8(wq[3][i].x, a.x, p3); p3 = dot4i8(wq[3][i].y, a.y, p3);
      p3 = dot4i8(wq[3][i].w, a.w, p3); p3 = dot4i8(wq[3][i].z, a.z, p3);
    }
    // quad reduce-transpose: stage 1 over xor16 (flips q2 bit0) keeps dims
    // with bit0 == my bit0; stage 2 over xor32 (flips bit1) keeps dim q2.
    int b0 = q2 & 1, b1 = q2 >> 1;
    int send0 = b0 ? p0 : p1, keep0 = b0 ? p1 : p0;   // dims {0,1}
    int send1 = b0 ? p2 : p3, keep1 = b0 ? p3 : p2;   // dims {2,3}
    int z0 = keep0 + __shfl_xor(send0, 16);           // dim b0
    int z1 = keep1 + __shfl_xor(send1, 16);           // dim 2+b0
    int zs = b1 ? z0 : z1, zk = b1 ? z1 : z0;
    int z  = zk + __shfl_xor(zs, 32);                 // dim 2*b1+b0 = q2
    float arg = (float)z * scale + fvb;
    float g = 1.f / (1.f + __expf(-arg));
    h = h + g * (nv - h);
    np[(size_t)t * D] = f2bf(h);          // overwrite Nn with H
    int q = __float2int_rn(h * 127.f);
    q = q < -127 ? -127 : (q > 127 ? 127 : q);
    hq[(t+1) & 1][e] = (char)q;
    nv = nv_n; fvb = fvb_n;
    // raw barrier: drain LDS only (global h-store may stay in flight)
    asm volatile("s_waitcnt lgkmcnt(0)\n\ts_barrier" ::: "memory");
  }
}

// ---------------- final gate_cell, pass 1: lru -> (in-place over Nng) -----
__global__ __launch_bounds__(256) void final1_k(const u16* __restrict__ xn,
                                                u16* __restrict__ Nng,        // tanh(h1@gWn), becomes lru
                                                const u16* __restrict__ Ffg,  // h1@gWif
                                                const u16* __restrict__ Ghf,  // xn@gWhf
                                                const float* __restrict__ gbhf){
  size_t i = (size_t)blockIdx.x * 256 + threadIdx.x;
  int e = (int)(i & (D - 1));
  float xnv = bf2f(xn[i]);
  float nv  = bf2f(Nng[i]);
  float arg = bf2f(Ghf[i]) + gbhf[e] + bf2f(Ffg[i]);
  float g = 1.f / (1.f + __expf(-arg));
  float lru = xnv + g * (nv - xnv);
  Nng[i] = f2bf(lru);
}

// ---------------- final pass 2: out = lru + x (fp32) ----------------------
__global__ __launch_bounds__(256) void final2_k(const u16* __restrict__ lru,
                                                const float* __restrict__ x,
                                                float* __restrict__ out){
  size_t i = (size_t)blockIdx.x * 256 + threadIdx.x;
  out[i] = bf2f(lru[i]) + x[i];
}

extern "C" void kernel_launch(void* const* d_in, const int* in_sizes, int n_in,
                              void* d_out, int out_size, void* d_ws, size_t ws_size,
                              hipStream_t stream){
  const float* x      = (const float*)d_in[0];
  const float* gamma  = (const float*)d_in[1];
  const float* g_Wn   = (const float*)d_in[2];
  const float* g_Wif  = (const float*)d_in[3];
  const float* g_Whf  = (const float*)d_in[4];
  const float* g_bhf  = (const float*)d_in[5];
  const float* l0_Wn  = (const float*)d_in[6];
  const float* l0_Wif = (const float*)d_in[7];
  const float* l0_Whf = (const float*)d_in[8];
  const float* l0_bhf = (const float*)d_in[9];
  const float* l1_Wn  = (const float*)d_in[10];
  const float* l1_Wif = (const float*)d_in[11];
  const float* l1_Whf = (const float*)d_in[12];
  const float* l1_bhf = (const float*)d_in[13];
  float* out = (float*)d_out;

  // ---- plane layout: P0,P1 in ws; P2,P3 inside d_out (2 bf16 planes = 134MB)
  char* ws = (char*)d_ws;
  const size_t PLANE = (size_t)BT * D * 2;      // 67.1 MB bf16 plane
  u16* P0 = (u16*)(ws);                         // xn (live to the end)
  u16* P1 = (u16*)(ws + PLANE);                 // Nn0/H0, then Nn_g, then lru
  u16* P2 = (u16*)d_out;                        // Ff planes
  u16* P3 = P2 + (size_t)BT * D;                // Nn1/H1, then Ghf

  char* wb = ws + 2*PLANE;
  const size_t WSZ = (size_t)D * D * 2;         // 512 KB per transposed bf16 weight
  u16* T_l0Wn  = (u16*)(wb + 0*WSZ);
  u16* T_l0Wif = (u16*)(wb + 1*WSZ);
  u16* T_gWhf  = (u16*)(wb + 2*WSZ);
  u16* T_l1Wn  = (u16*)(wb + 3*WSZ);
  u16* T_l1Wif = (u16*)(wb + 4*WSZ);
  u16* T_gWn   = (u16*)(wb + 5*WSZ);
  u16* T_gWif  = (u16*)(wb + 6*WSZ);
  int*   Wq0 = (int*)  (wb + 7*WSZ);
  int*   Wq1 = (int*)  (wb + 7*WSZ + (size_t)D*D);
  float* sc0 = (float*)(wb + 7*WSZ + 2*(size_t)D*D);
  float* sc1 = (float*)(wb + 7*WSZ + 2*(size_t)D*D + D*4);

  dim3 tb(256);
  // weight prep: 7 transposes in ONE dispatch, both quants in ONE dispatch
  transpose7_k<<<dim3(16, 16, 7), tb, 0, stream>>>(
      l0_Wn, l0_Wif, g_Whf, l1_Wn, l1_Wif, g_Wn, g_Wif,
      T_l0Wn, T_l0Wif, T_gWhf, T_l1Wn, T_l1Wif, T_gWn, T_gWif);
  quant2_k<<<2*D, 64, 0, stream>>>(l0_Whf, l1_Whf, Wq0, Wq1, sc0, sc1);

  rmsnorm_k<<<BT, 256, 0, stream>>>(x, gamma, P0);

  dim3 gg(BT/128, D/128);
  // layer 0: Nn0 + Ff0 share A = xn -> one dual-B dispatch
  gemm_bt2_k<<<gg, tb, 0, stream>>>(P0, T_l0Wn, T_l0Wif, P1, P2);
  lru_scan_k<<<BATCH, 512, 0, stream>>>(P1, P2, Wq0, sc0, l0_bhf);  // H0 -> P1
  // layer 1: Nn1 + Ff1 share A = H0
  gemm_bt2_k<<<gg, tb, 0, stream>>>(P1, T_l1Wn, T_l1Wif, P3, P2);
  lru_scan_k<<<BATCH, 512, 0, stream>>>(P3, P2, Wq1, sc1, l1_bhf);  // H1 -> P3
  // gate cell: Nn_g + Ff_g share A = H1 (H0 dead -> P1, Ff1 dead -> P2)
  gemm_bt2_k<<<gg, tb, 0, stream>>>(P3, T_gWn, T_gWif, P1, P2);
  gemm_bt_k<<<gg, tb, 0, stream>>>(P0, T_gWhf, P3, 0);    // Ghf (H1 dead)

  final1_k<<<BT*D/256, 256, 0, stream>>>(P0, P1, P2, P3, g_bhf);  // lru -> P1
  final2_k<<<BT*D/256, 256, 0, stream>>>(P1, x, out);
}

// Round 9
// 3434.843 us; speedup vs baseline: 1.4375x; 1.2798x over previous
//
#include <hip/hip_runtime.h>
#include <stdint.h>

#define D 512
#define BATCH 32
#define TT 2048
#define BT (BATCH*TT)   // 65536

typedef unsigned short u16;
typedef __attribute__((ext_vector_type(8))) short bf16x8;
typedef __attribute__((ext_vector_type(4))) float f32x4;

__device__ __forceinline__ float bf2f(u16 u){
  union { unsigned int i; float f; } v; v.i = ((unsigned int)u) << 16; return v.f;
}
__device__ __forceinline__ u16 f2bf(float f){
  union { float f; unsigned int i; } v; v.f = f;
  unsigned int r = (v.i + 0x7fffu + ((v.i >> 16) & 1u)) >> 16;
  return (u16)r;
}

__device__ __forceinline__ int dot4i8(int a, int b, int c){
#if __has_builtin(__builtin_amdgcn_sdot4)
  return __builtin_amdgcn_sdot4(a, b, c, false);
#else
  c += (int)(char)(a      ) * (int)(char)(b      );
  c += (int)(char)(a >>  8) * (int)(char)(b >>  8);
  c += (int)(char)(a >> 16) * (int)(char)(b >> 16);
  c += (int)(char)(a >> 24) * (int)(char)(b >> 24);
  return c;
#endif
}

// ---- device-scope producer/consumer handshake ----------------------------
__device__ __forceinline__ void spin_wait_ge(const int* p, int target){
  // relaxed polling (no per-poll cache maintenance), one acquire fence after
  int iters = 0;
  while (__hip_atomic_load(p, __ATOMIC_RELAXED, __HIP_MEMORY_SCOPE_AGENT) < target){
    __builtin_amdgcn_s_sleep(16);
    if (++iters > 4000000) break;   // failsafe: fail loud, never hang forever
  }
  __builtin_amdgcn_fence(__ATOMIC_ACQUIRE, "agent");
}

// ---------------- rmsnorm: xn = x/max(||x||,1e-12) * sqrt(D) * (gamma+1) ---
__global__ __launch_bounds__(256) void rmsnorm_k(const float* __restrict__ x,
                                                 const float* __restrict__ gamma,
                                                 u16* __restrict__ xn){
  int row = blockIdx.x;
  int t = threadIdx.x;
  const float* xr = x + (size_t)row * D;
  float v0 = xr[t];
  float v1 = xr[t + 256];
  float s = v0*v0 + v1*v1;
  #pragma unroll
  for (int o = 32; o > 0; o >>= 1) s += __shfl_down(s, o);
  __shared__ float red[4];
  int lane = t & 63, wv = t >> 6;
  if (lane == 0) red[wv] = s;
  __syncthreads();
  float tot = red[0] + red[1] + red[2] + red[3];
  float n = fmaxf(sqrtf(tot), 1e-12f);
  float sc = 22.627416997969522f / n;   // sqrt(512)
  u16* o_ = xn + (size_t)row * D;
  o_[t]       = f2bf(v0 * sc * (gamma[t] + 1.f));
  o_[t + 256] = f2bf(v1 * sc * (gamma[t + 256] + 1.f));
}

// -------- 512x512 transpose + fp32->bf16 convert (dst[n][k] = src[k][n]) ---
__global__ __launch_bounds__(256) void transpose_k(const float* __restrict__ src,
                                                   u16* __restrict__ dst){
  __shared__ u16 tile[32][33];
  int bx = blockIdx.x * 32, by = blockIdx.y * 32;
  int tx = threadIdx.x & 31, ty = threadIdx.x >> 5;   // 32 x 8
  #pragma unroll
  for (int i = 0; i < 32; i += 8)
    tile[ty + i][tx] = f2bf(src[(size_t)(by + ty + i) * D + bx + tx]);
  __syncthreads();
  #pragma unroll
  for (int i = 0; i < 32; i += 8)
    dst[(size_t)(bx + ty + i) * D + by + tx] = tile[tx][ty + i];
}

// -------- per-column int8 quantization of Whf (fp32 in) -------------------
__global__ __launch_bounds__(64) void quant_col_k(const float* __restrict__ W,
                                                  int* __restrict__ Wq,
                                                  float* __restrict__ sc){
  int e = blockIdx.x;
  int lane = threadIdx.x;
  float w[8];
  float m = 0.f;
  #pragma unroll
  for (int j = 0; j < 8; j++){
    w[j] = W[(size_t)(lane*8 + j) * D + e];
    m = fmaxf(m, fabsf(w[j]));
  }
  #pragma unroll
  for (int o = 32; o > 0; o >>= 1) m = fmaxf(m, __shfl_xor(m, o));
  float inv = (m > 0.f) ? (127.f / m) : 0.f;
  int q[8];
  #pragma unroll
  for (int j = 0; j < 8; j++){
    int v = __float2int_rn(w[j] * inv);
    v = v < -127 ? -127 : (v > 127 ? 127 : v);
    q[j] = v & 0xff;
  }
  int p0 = q[0] | (q[1] << 8) | (q[2] << 16) | (q[3] << 24);
  int p1 = q[4] | (q[5] << 8) | (q[6] << 16) | (q[7] << 24);
  Wq[e*128 + lane*2]     = p0;
  Wq[e*128 + lane*2 + 1] = p1;
  if (lane == 0) sc[e] = m / (127.f * 127.f);
}

// ---------------- bf16 GEMM: C[m][n] = sum_k A[m][k]*Bt[n][k] -------------
// (round-3 proven, unchanged)
__global__ __launch_bounds__(256) void gemm_bt_k(const u16* __restrict__ A,
                                                 const u16* __restrict__ Bt,
                                                 u16* __restrict__ C,
                                                 int do_tanh){
  __shared__ __align__(16) u16 As[128*32];
  __shared__ __align__(16) u16 Bs[128*32];
  int tid = threadIdx.x;
  int bm = blockIdx.x, bn = blockIdx.y;
  int wv = tid >> 6, lane = tid & 63;
  int wm = (wv & 1) * 64, wn = (wv >> 1) * 64;
  int m0 = lane & 15, quad = lane >> 4;
  f32x4 acc[4][4];
  #pragma unroll
  for (int i = 0; i < 4; i++)
    #pragma unroll
    for (int j = 0; j < 4; j++){
      f32x4 z = {0.f, 0.f, 0.f, 0.f};
      acc[i][j] = z;
    }
  const size_t arow = (size_t)bm * 128;
  const size_t brow = (size_t)bn * 128;
  for (int k0 = 0; k0 < D; k0 += 32){
    __syncthreads();
    #pragma unroll
    for (int i = 0; i < 2; i++){
      int c = tid + 256*i;
      int r = c >> 2, ko = (c & 3) * 8;
      ((int4*)As)[c] = *(const int4*)(A  + (arow + r) * D + k0 + ko);
      ((int4*)Bs)[c] = *(const int4*)(Bt + (brow + r) * D + k0 + ko);
    }
    __syncthreads();
    bf16x8 af[4], bfr[4];
    #pragma unroll
    for (int i = 0; i < 4; i++){
      af[i]  = *(const bf16x8*)(As + (wm + i*16 + m0) * 32 + quad*8);
      bfr[i] = *(const bf16x8*)(Bs + (wn + i*16 + m0) * 32 + quad*8);
    }
    #pragma unroll
    for (int i = 0; i < 4; i++)
      #pragma unroll
      for (int j = 0; j < 4; j++)
        acc[i][j] = __builtin_amdgcn_mfma_f32_16x16x32_bf16(af[i], bfr[j], acc[i][j], 0, 0, 0);
  }
  #pragma unroll
  for (int i = 0; i < 4; i++)
    #pragma unroll
    for (int j = 0; j < 4; j++)
      #pragma unroll
      for (int r = 0; r < 4; r++){
        size_t row = arow + wm + i*16 + quad*4 + r;
        int col = bn*128 + wn + j*16 + m0;
        float v = acc[i][j][r];
        if (do_tanh) v = tanhf(v);
        C[row * D + col] = f2bf(v);
      }
}

// ---------------- scan core (round-3 proven body, verbatim math) ----------
// prog_pub  != null: publish progress (rows done) every 64 steps (release).
// prog_wait != null: before each 64-row chunk, wait until input rows
//                    [0, min(t+128,TT)) are published (acquire).
__device__ __forceinline__ void scan_core(u16* __restrict__ Nn,
                                          const u16* __restrict__ Ff,
                                          const int* __restrict__ Wq,
                                          const float* __restrict__ sc,
                                          const float* __restrict__ bhf,
                                          int b, int tid, char* smem,
                                          int* prog_pub, const int* prog_wait){
  int wv = tid >> 6, l = tid & 63;
  int m  = l & 15;          // quad id within wave
  int q2 = l >> 4;          // K-chunk = final dim offset
  int base_e = wv*64 + m*4;
  int e = base_e + q2;

  int4 wq[4][8];
  #pragma unroll
  for (int j = 0; j < 4; j++){
    const int* wp = Wq + (size_t)(base_e + j) * 128 + q2*32;
    #pragma unroll
    for (int i = 0; i < 8; i++) wq[j][i] = ((const int4*)wp)[i];
  }
  float scale = sc[e];
  float bias  = bhf[e];

  char (*hq)[512] = (char(*)[512])smem;
  if (tid < 128) ((int*)smem)[tid] = 0;
  float h = 0.f;
  const size_t base = (size_t)b * TT * D + e;
  u16* np = Nn + base;
  const u16* fp = Ff + base;

  if (prog_wait) spin_wait_ge(prog_wait + b, 128);
  float nv  = bf2f(np[0]);
  float fvb = bf2f(fp[0]) + bias;
  __syncthreads();

  for (int t = 0; t < TT; t++){
    if (prog_wait && t && (t & 63) == 0){
      int target = t + 128; if (target > TT) target = TT;
      spin_wait_ge(prog_wait + b, target);
    }
    float nv_n = 0.f, fvb_n = 0.f;
    if (t < TT - 1){
      nv_n  = bf2f(np[(size_t)(t+1) * D]);
      fvb_n = bf2f(fp[(size_t)(t+1) * D]) + bias;
    }
    const char* hb = hq[t & 1] + q2*128;
    int p0 = 0, p1 = 0, p2 = 0, p3 = 0;
    #pragma unroll
    for (int i = 0; i < 8; i++){
      int4 a = ((const int4*)hb)[i];
      p0 = dot4i8(wq[0][i].x, a.x, p0); p0 = dot4i8(wq[0][i].y, a.y, p0);
      p0 = dot4i8(wq[0][i].z, a.z, p0); p0 = dot4i8(wq[0][i].w, a.w, p0);
      p1 = dot4i8(wq[1][i].x, a.x, p1); p1 = dot4i8(wq[1][i].y, a.y, p1);
      p1 = dot4i8(wq[1][i].z, a.z, p1); p1 = dot4i8(wq[1][i].w, a.w, p1);
      p2 = dot4i8(wq[2][i].x, a.x, p2); p2 = dot4i8(wq[2][i].y, a.y, p2);
      p2 = dot4i8(wq[2][i].z, a.z, p2); p2 = dot4i8(wq[2][i].w, a.w, p2);
      p3 = dot4i8(wq[3][i].x, a.x, p3); p3 = dot4i8(wq[3][i].y, a.y, p3);
      p3 = dot4i8(wq[3][i].z, a.z, p3); p3 = dot4i8(wq[3][i].w, a.w, p3);
    }
    int b0 = q2 & 1, b1 = q2 >> 1;
    int send0 = b0 ? p0 : p1, keep0 = b0 ? p1 : p0;
    int send1 = b0 ? p2 : p3, keep1 = b0 ? p3 : p2;
    int z0 = keep0 + __shfl_xor(send0, 16);
    int z1 = keep1 + __shfl_xor(send1, 16);
    int zs = b1 ? z0 : z1, zk = b1 ? z1 : z0;
    int z  = zk + __shfl_xor(zs, 32);
    float arg = (float)z * scale + fvb;
    float g = 1.f / (1.f + __expf(-arg));
    h = h + g * (nv - h);
    np[(size_t)t * D] = f2bf(h);          // overwrite Nn with H
    int q = __float2int_rn(h * 127.f);
    q = q < -127 ? -127 : (q > 127 ? 127 : q);
    hq[(t+1) & 1][e] = (char)q;
    nv = nv_n; fvb = fvb_n;
    asm volatile("s_waitcnt lgkmcnt(0)\n\ts_barrier" ::: "memory");
    if (prog_pub && (t & 63) == 63){
      asm volatile("s_waitcnt vmcnt(0)" ::: "memory");   // drain own H stores
      __syncthreads();                                   // all lanes drained
      if (tid == 0)
        __hip_atomic_store(prog_pub + b, t + 1, __ATOMIC_RELEASE,
                           __HIP_MEMORY_SCOPE_AGENT);
    }
  }
}

// -------- fused middle: scan0 || chunked GEMM(Nn1,Ff1) || scan1 -----------
// 96 blocks (<=256 CUs -> all co-resident; wait-DAG A->B->C acyclic):
//   blocks  0..31  Role A: scan0 batch b  (P1: Nn0 -> H0), publish prog0
//   blocks 32..63  Role B: per 64-row chunk, wait prog0, compute
//                  Nn1 = tanh(H0@Wn1^T) -> P3, Ff1 = H0@Wif1^T -> P1
//                  (over consumed H0 rows), publish prog1
//   blocks 64..95  Role C: scan1 batch b (P3: Nn1 -> H1, Ff=P1), wait prog1
// GEMM uses the proven fragment pattern, K-order identical to gemm_bt_k
// -> all results bit-identical to the unfused pipeline.
#define LDA 260   // 256 + 4 u16 pad: 520-B row stride -> <=2-way banks (free)
__global__ __launch_bounds__(512, 1) void fused_mid_k(
    u16* __restrict__ P1,          // Nn0 -> H0 -> Ff1
    const u16* __restrict__ P2,    // Ff0
    u16* __restrict__ P3,          // Nn1 -> H1
    const u16* __restrict__ Wn1t, const u16* __restrict__ Wif1t,
    const int* __restrict__ Wq0, const float* __restrict__ sc0,
    const float* __restrict__ bhf0,
    const int* __restrict__ Wq1, const float* __restrict__ sc1,
    const float* __restrict__ bhf1,
    int* __restrict__ prog0, int* __restrict__ prog1){
  __shared__ __align__(16) char smem[64 * LDA * 2];   // 33280 B (scan uses 1KB)
  int blk = blockIdx.x, tid = threadIdx.x;

  if (blk < 32){                      // ---- Role A: scan0 (producer)
    scan_core(P1, P2, Wq0, sc0, bhf0, blk, tid, smem, prog0, nullptr);
  } else if (blk < 64){               // ---- Role B: chunked dual GEMM
    int b = blk - 32;
    u16* As = (u16*)smem;             // [64][LDA]
    const size_t bbase = (size_t)b * TT * D;
    int wv = tid >> 6, lane = tid & 63;
    int m0 = lane & 15, quad = lane >> 4;
    int wn = wv * 64;                 // wave's n-strip (8 x 64 = 512)
    for (int c = 0; c < TT/64; c++){
      int r0 = c * 64;
      spin_wait_ge(prog0 + b, r0 + 64);
      f32x4 accA[4][4], accB[4][4];
      #pragma unroll
      for (int i = 0; i < 4; i++)
        #pragma unroll
        for (int j = 0; j < 4; j++){
          f32x4 zz = {0.f, 0.f, 0.f, 0.f};
          accA[i][j] = zz; accB[i][j] = zz;
        }
      for (int kh = 0; kh < 2; kh++){
        __syncthreads();              // previous compute done before restage
        // stage rows r0..r0+63, k in [kh*256, kh*256+256)
        #pragma unroll
        for (int j = 0; j < 4; j++){
          int idx = tid + 512*j;      // 0..2047 int4s; 32 int4 per row
          int row = idx >> 5, k8 = idx & 31;
          *(int4*)(As + row*LDA + k8*8) =
            *(const int4*)(P1 + bbase + (size_t)(r0 + row)*D + kh*256 + k8*8);
        }
        __syncthreads();
        #pragma unroll
        for (int ks = 0; ks < 8; ks++){
          int k0g = kh*256 + ks*32, k0l = ks*32;
          bf16x8 af[4], bA[4], bB[4];
          #pragma unroll
          for (int i = 0; i < 4; i++)
            af[i] = *(const bf16x8*)(As + (i*16 + m0)*LDA + k0l + quad*8);
          #pragma unroll
          for (int j = 0; j < 4; j++){
            size_t n = (size_t)(wn + j*16 + m0);
            bA[j] = *(const bf16x8*)(Wn1t  + n*D + k0g + quad*8);
            bB[j] = *(const bf16x8*)(Wif1t + n*D + k0g + quad*8);
          }
          #pragma unroll
          for (int i = 0; i < 4; i++)
            #pragma unroll
            for (int j = 0; j < 4; j++){
              accA[i][j] = __builtin_amdgcn_mfma_f32_16x16x32_bf16(af[i], bA[j], accA[i][j], 0, 0, 0);
              accB[i][j] = __builtin_amdgcn_mfma_f32_16x16x32_bf16(af[i], bB[j], accB[i][j], 0, 0, 0);
            }
        }
      }
      // epilogue: Nn1 (tanh) -> P3; Ff1 -> P1 (over consumed H0 rows)
      #pragma unroll
      for (int i = 0; i < 4; i++)
        #pragma unroll
        for (int j = 0; j < 4; j++)
          #pragma unroll
          for (int r = 0; r < 4; r++){
            size_t row = (size_t)(r0 + i*16 + quad*4 + r);
            int col = wn + j*16 + m0;
            P3[bbase + row*D + col] = f2bf(tanhf(accA[i][j][r]));
            P1[bbase + row*D + col] = f2bf(accB[i][j][r]);
          }
      asm volatile("s_waitcnt vmcnt(0)" ::: "memory");
      __syncthreads();
      if (tid == 0)
        __hip_atomic_store(prog1 + b, r0 + 64, __ATOMIC_RELEASE,
                           __HIP_MEMORY_SCOPE_AGENT);
    }
  } else {                            // ---- Role C: scan1 (consumer)
    scan_core(P3, P1, Wq1, sc1, bhf1, blk - 64, tid, smem, nullptr, prog1);
  }
}

// ---------------- flag reset (per launch / graph replay) ------------------
__global__ __launch_bounds__(64) void zero_flags_k(int* __restrict__ f){
  f[threadIdx.x] = 0;
}

// ---------------- final gate_cell, pass 1: lru -> (in-place over Nng) -----
__global__ __launch_bounds__(256) void final1_k(const u16* __restrict__ xn,
                                                u16* __restrict__ Nng,
                                                const u16* __restrict__ Ffg,
                                                const u16* __restrict__ Ghf,
                                                const float* __restrict__ gbhf){
  size_t i = (size_t)blockIdx.x * 256 + threadIdx.x;
  int e = (int)(i & (D - 1));
  float xnv = bf2f(xn[i]);
  float nv  = bf2f(Nng[i]);
  float arg = bf2f(Ghf[i]) + gbhf[e] + bf2f(Ffg[i]);
  float g = 1.f / (1.f + __expf(-arg));
  float lru = xnv + g * (nv - xnv);
  Nng[i] = f2bf(lru);
}

// ---------------- final pass 2: out = lru + x (fp32) ----------------------
__global__ __launch_bounds__(256) void final2_k(const u16* __restrict__ lru,
                                                const float* __restrict__ x,
                                                float* __restrict__ out){
  size_t i = (size_t)blockIdx.x * 256 + threadIdx.x;
  out[i] = bf2f(lru[i]) + x[i];
}

extern "C" void kernel_launch(void* const* d_in, const int* in_sizes, int n_in,
                              void* d_out, int out_size, void* d_ws, size_t ws_size,
                              hipStream_t stream){
  const float* x      = (const float*)d_in[0];
  const float* gamma  = (const float*)d_in[1];
  const float* g_Wn   = (const float*)d_in[2];
  const float* g_Wif  = (const float*)d_in[3];
  const float* g_Whf  = (const float*)d_in[4];
  const float* g_bhf  = (const float*)d_in[5];
  const float* l0_Wn  = (const float*)d_in[6];
  const float* l0_Wif = (const float*)d_in[7];
  const float* l0_Whf = (const float*)d_in[8];
  const float* l0_bhf = (const float*)d_in[9];
  const float* l1_Wn  = (const float*)d_in[10];
  const float* l1_Wif = (const float*)d_in[11];
  const float* l1_Whf = (const float*)d_in[12];
  const float* l1_bhf = (const float*)d_in[13];
  float* out = (float*)d_out;

  // ---- plane layout: P0,P1 in ws; P2,P3 inside d_out (2 bf16 planes)
  char* ws = (char*)d_ws;
  const size_t PLANE = (size_t)BT * D * 2;      // 67.1 MB bf16 plane
  u16* P0 = (u16*)(ws);                         // xn (live to the end)
  u16* P1 = (u16*)(ws + PLANE);                 // Nn0 -> H0 -> Ff1, then Nn_g/lru
  u16* P2 = (u16*)d_out;                        // Ff0, then Ff_g
  u16* P3 = P2 + (size_t)BT * D;                // Nn1 -> H1, then Ghf

  char* wb = ws + 2*PLANE;
  const size_t WSZ = (size_t)D * D * 2;         // 512 KB per transposed weight
  u16* T_l0Wn  = (u16*)(wb + 0*WSZ);
  u16* T_l0Wif = (u16*)(wb + 1*WSZ);
  u16* T_gWhf  = (u16*)(wb + 2*WSZ);
  u16* T_l1Wn  = (u16*)(wb + 3*WSZ);
  u16* T_l1Wif = (u16*)(wb + 4*WSZ);
  u16* T_gWn   = (u16*)(wb + 5*WSZ);
  u16* T_gWif  = (u16*)(wb + 6*WSZ);
  int*   Wq0 = (int*)  (wb + 7*WSZ);
  int*   Wq1 = (int*)  (wb + 7*WSZ + (size_t)D*D);
  float* sc0 = (float*)(wb + 7*WSZ + 2*(size_t)D*D);
  float* sc1 = (float*)(wb + 7*WSZ + 2*(size_t)D*D + D*4);
  int*  prog = (int*)  (wb + 7*WSZ + 2*(size_t)D*D + 2*D*4);  // prog0[32]+prog1[32]

  dim3 tb(256), tg(16, 16);
  // weight prep (R3-proven separate tiny dispatches)
  transpose_k<<<tg, tb, 0, stream>>>(l0_Wn,  T_l0Wn);
  transpose_k<<<tg, tb, 0, stream>>>(l0_Wif, T_l0Wif);
  transpose_k<<<tg, tb, 0, stream>>>(g_Whf,  T_gWhf);
  transpose_k<<<tg, tb, 0, stream>>>(l1_Wn,  T_l1Wn);
  transpose_k<<<tg, tb, 0, stream>>>(l1_Wif, T_l1Wif);
  transpose_k<<<tg, tb, 0, stream>>>(g_Wn,   T_gWn);
  transpose_k<<<tg, tb, 0, stream>>>(g_Wif,  T_gWif);
  quant_col_k<<<512, 64, 0, stream>>>(l0_Whf, Wq0, sc0);
  quant_col_k<<<512, 64, 0, stream>>>(l1_Whf, Wq1, sc1);
  zero_flags_k<<<1, 64, 0, stream>>>(prog);

  rmsnorm_k<<<BT, 256, 0, stream>>>(x, gamma, P0);

  dim3 gg(BT/128, D/128);
  // layer-0 projections (R3-proven)
  gemm_bt_k<<<gg, tb, 0, stream>>>(P0, T_l0Wn,  P1, 1);   // Nn0
  gemm_bt_k<<<gg, tb, 0, stream>>>(P0, T_l0Wif, P2, 0);   // Ff0
  // fused middle: scan0 || GEMM(Nn1,Ff1) || scan1
  fused_mid_k<<<96, 512, 0, stream>>>(P1, P2, P3, T_l1Wn, T_l1Wif,
                                      Wq0, sc0, l0_bhf, Wq1, sc1, l1_bhf,
                                      prog, prog + 32);
  // gate cell projections (Ff1 dead -> P1, Ff0 dead -> P2, then H1 dead -> P3)
  gemm_bt_k<<<gg, tb, 0, stream>>>(P3, T_gWn,  P1, 1);    // Nn_g
  gemm_bt_k<<<gg, tb, 0, stream>>>(P3, T_gWif, P2, 0);    // Ff_g
  gemm_bt_k<<<gg, tb, 0, stream>>>(P0, T_gWhf, P3, 0);    // Ghf

  final1_k<<<BT*D/256, 256, 0, stream>>>(P0, P1, P2, P3, g_bhf);  // lru -> P1
  final2_k<<<BT*D/256, 256, 0, stream>>>(P1, x, out);
}